// Round 3
// baseline (1205.529 us; speedup 1.0000x reference)
//
#include <hip/hip_runtime.h>

// RecyclingEmbedder: out[i][j][p] = b[p] + (bin(d_ij) fired ? W[p][bin] : 0)
// d_ij = |x_i - x_j|^2, bins = linspace(3.25,20.75,15)^2, strict >lower & <upper.
// Output = 16-row table lookup -> pure write-BW problem (1.208 GB fp32).
//
// R2 (session 1): nontemporal stores ~1.0 TB/s -> plain stores.
// R1: occupancy 24->32 waves/CU: null (-18us) -> not latency-bound.
// R2 (this session): infra failure ("container failed twice"), no signal.
// R3 theory (T): per-block private 384KB write regions scatter the instantaneous
// write stream across the whole 1.2GB -> HBM row thrash -> ~3.1 TB/s (half of
// the harness fill's 6.26 TB/s, which sweeps LINEARLY via flat grid-stride).
// Fix: imitate the fill exactly. Two dispatches:
//   1) prep: per-pair bin idx (1536^2 bytes) + expanded 16x128 table -> d_ws
//   2) stream: flat grid-stride writer, 2048 blocks; per f32x4:
//      broadcast ubyte idx load (L2) + 16B table load (L1, within=flat&31 is
//      thread-constant) + plain dwordx4 store. No LDS, no syncthreads.

#define NBINS 15
#define NPTS  1536
#define DPAIR 128
#define NPAIR (NPTS * NPTS)                  // 2359296 pairs
#define TOT_F4 (NPAIR * (DPAIR / 4))         // 75497472 output float4
#define SBLOCKS 2048
#define NT (SBLOCKS * 256)                   // 524288 threads
#define NITER (TOT_F4 / NT)                  // 144, exact (no tail)

#define TAB_BYTES (16 * DPAIR * 4)           // 8192
#define WS_NEEDED (TAB_BYTES + NPAIR)        // 8 KB + 2.36 MB

typedef float f32x4 __attribute__((ext_vector_type(4)));

// ---------------- dispatch 1: prep (idx table + expanded row table) ---------
__global__ __launch_bounds__(256) void prep_kernel(
    const float* __restrict__ x,   // [NPTS,3]
    const float* __restrict__ W,   // [DPAIR,NBINS] row-major
    const float* __restrict__ b,   // [DPAIR]
    float* __restrict__ tab,       // [16*DPAIR] in ws
    unsigned char* __restrict__ idx) {  // [NPAIR] in ws
    const int i = blockIdx.x;
    const int t = threadIdx.x;

    // squared bin edges: exact multiples of 0.25 -> exact fp32; squaring
    // rounds identically to numpy's **2 in float32.
    float bins[NBINS];
#pragma unroll
    for (int k = 0; k < NBINS; ++k) {
        float e = 3.25f + 1.25f * (float)k;
        bins[k] = e * e;
    }

    // Block 0 additionally builds the 16-row table (row 0 = b, row k = b+W[:,k-1]).
    if (i == 0) {
        for (int e = t; e < 16 * DPAIR; e += 256) {
            int row = e >> 7;            // 0..15
            int p   = e & (DPAIR - 1);
            float v = b[p];
            if (row > 0) v += W[p * NBINS + (row - 1)];
            tab[e] = v;
        }
    }

    const float xi0 = x[i * 3 + 0];
    const float xi1 = x[i * 3 + 1];
    const float xi2 = x[i * 3 + 2];
    for (int j = t; j < NPTS; j += 256) {
        float d;
        {
            // Bit-exact vs numpy: individually-rounded squares, left-to-right
            // sum, no fma contraction.
#pragma clang fp contract(off)
            float dx = xi0 - x[j * 3 + 0];
            float dy = xi1 - x[j * 3 + 1];
            float dz = xi2 - x[j * 3 + 2];
            d = dx * dx + dy * dy + dz * dz;
        }
        int cnt = 0, eq = 0;
#pragma unroll
        for (int k = 0; k < NBINS; ++k) {
            cnt += (d > bins[k]) ? 1 : 0;
            eq  |= (d == bins[k]) ? 1 : 0;
        }
        // exact edge hit -> one-hot all zero -> row 0 (b only)
        idx[i * NPTS + j] = (unsigned char)(eq ? 0 : cnt);
    }
}

// ---------------- dispatch 2: fill-pattern linear-sweep writer --------------
__global__ __launch_bounds__(256, 8) void stream_kernel(
    const float* __restrict__ tab,           // [16*DPAIR] in ws
    const unsigned char* __restrict__ idx,   // [NPAIR] in ws
    float* __restrict__ out) {               // [NPTS,NPTS,DPAIR]
    const f32x4* tab4 = (const f32x4*)tab;
    f32x4* out4 = (f32x4*)out;

    const unsigned flat = blockIdx.x * 256u + threadIdx.x;
    const unsigned w = flat & 31u;           // thread-constant f4 lane in feature row

    // Whole GPU sweeps one contiguous 8 MB window per iteration (fill pattern).
#pragma unroll 4
    for (int it = 0; it < NITER; ++it) {
        unsigned g = flat + (unsigned)it * (unsigned)NT;  // global f4 index
        unsigned p = g >> 5;                 // pair index (i*NPTS+j)
        unsigned id = idx[p];                // 32-lane broadcast, L2-resident
        out4[g] = tab4[id * 32u + w];        // 16B from L1-resident 8KB table
    }
}

// ---------------- fallback (R1 kernel) if ws is too small -------------------
#define JSPLIT 2
#define JCHUNK (NPTS / JSPLIT)
#define CHUNK_F4 (JCHUNK * DPAIR / 4)

__global__ __launch_bounds__(256, 8) void recycling_embedder_fallback(
    const float* __restrict__ x,
    const float* __restrict__ W,
    const float* __restrict__ b,
    float* __restrict__ out) {
    __shared__ float table[16 * DPAIR];
    __shared__ unsigned short offs[JCHUNK];

    const int i    = blockIdx.x >> 1;
    const int half = blockIdx.x & 1;
    const int t    = threadIdx.x;

    float bins[NBINS];
#pragma unroll
    for (int k = 0; k < NBINS; ++k) {
        float e = 3.25f + 1.25f * (float)k;
        bins[k] = e * e;
    }

    for (int e = t; e < 16 * DPAIR; e += 256) {
        int row = e >> 7;
        int p   = e & (DPAIR - 1);
        float v = b[p];
        if (row > 0) v += W[p * NBINS + (row - 1)];
        table[e] = v;
    }

    const float xi0 = x[i * 3 + 0];
    const float xi1 = x[i * 3 + 1];
    const float xi2 = x[i * 3 + 2];
    const int j0 = half * JCHUNK;
    for (int jj = t; jj < JCHUNK; jj += 256) {
        int j = j0 + jj;
        float d;
        {
#pragma clang fp contract(off)
            float dx = xi0 - x[j * 3 + 0];
            float dy = xi1 - x[j * 3 + 1];
            float dz = xi2 - x[j * 3 + 2];
            d = dx * dx + dy * dy + dz * dz;
        }
        int cnt = 0, eq = 0;
#pragma unroll
        for (int k = 0; k < NBINS; ++k) {
            cnt += (d > bins[k]) ? 1 : 0;
            eq  |= (d == bins[k]) ? 1 : 0;
        }
        int bidx = eq ? 0 : cnt;
        offs[jj] = (unsigned short)(bidx * (DPAIR / 4));
    }
    __syncthreads();

    const f32x4* table4 = (const f32x4*)table;
    f32x4* ochunk = (f32x4*)out
                  + (size_t)i * (NPTS * DPAIR / 4)
                  + (size_t)(j0 * (DPAIR / 4));
#pragma unroll 4
    for (int l = t; l < CHUNK_F4; l += 256) {
        int jj     = l >> 5;
        int within = l & 31;
        ochunk[l] = table4[offs[jj] + within];
    }
}

extern "C" void kernel_launch(void* const* d_in, const int* in_sizes, int n_in,
                              void* d_out, int out_size, void* d_ws, size_t ws_size,
                              hipStream_t stream) {
    const float* x = (const float*)d_in[0];
    const float* W = (const float*)d_in[1];
    const float* b = (const float*)d_in[2];
    float* out = (float*)d_out;

    if (ws_size >= (size_t)WS_NEEDED && d_ws != nullptr) {
        float* tab = (float*)d_ws;
        unsigned char* idx = (unsigned char*)d_ws + TAB_BYTES;

        // Dispatch 1: per-pair bin index + expanded table (~15 us).
        prep_kernel<<<dim3(NPTS), dim3(256), 0, stream>>>(x, W, b, tab, idx);
        // Dispatch 2: linear-sweep writer, identical traffic shape to the
        // 6.26 TB/s harness fill. 2048 blocks x 144 iterations, exact.
        stream_kernel<<<dim3(SBLOCKS), dim3(256), 0, stream>>>(tab, idx, out);
    } else {
        recycling_embedder_fallback<<<dim3(NPTS * JSPLIT), dim3(256), 0, stream>>>(
            x, W, b, out);
    }
}